// Round 1
// baseline (943.328 us; speedup 1.0000x reference)
//
#include <hip/hip_runtime.h>
#include <math.h>

// Problem constants (fixed by the reference)
#define NPTS 500000
#define SCALE 0.35355339059327373f   // 1/sqrt(8)
#define NTILES 7813                  // ceil(500000/64)
#define TPB 4                        // tiles per block
#define GRID ((NTILES + TPB - 1) / TPB)
#define Q4TOT 8000000                // NPTS*16 float4's in q / e / out

// ws layout (float offsets) — unchanged:
// [0,4096)      WqT[k][c] = Wq[c][k]
// [4096,8192)   WoT[c][c'] = Wo[c'][c]
// [8192,8704)   khs[b][c] = (k@Wk.T + bk)*scale
// [8704,9216)   vh[b][c]  = v@Wv.T + bv
// [9216,10240)  z as double[512]  (byte offset 36864, 8-aligned)

#define FMA4(A, S, W) do { A.x = fmaf(S, W.x, A.x); A.y = fmaf(S, W.y, A.y); \
                           A.z = fmaf(S, W.z, A.z); A.w = fmaf(S, W.w, A.w); } while (0)

// 16 k-steps: a0..a3 are q[p][16ky..16ky+16) chunks, wr[] is the per-lane W fragment.
#define FMABLK(A, a0, a1, a2, a3) do { \
    FMA4(A, a0.x, wr[0]);  FMA4(A, a0.y, wr[1]);  FMA4(A, a0.z, wr[2]);  FMA4(A, a0.w, wr[3]);  \
    FMA4(A, a1.x, wr[4]);  FMA4(A, a1.y, wr[5]);  FMA4(A, a1.z, wr[6]);  FMA4(A, a1.w, wr[7]);  \
    FMA4(A, a2.x, wr[8]);  FMA4(A, a2.y, wr[9]);  FMA4(A, a2.z, wr[10]); FMA4(A, a2.w, wr[11]); \
    FMA4(A, a3.x, wr[12]); FMA4(A, a3.y, wr[13]); FMA4(A, a3.z, wr[14]); FMA4(A, a3.w, wr[15]); \
} while (0)

__global__ void prep_kernel(const float* __restrict__ kin, const float* __restrict__ vin,
                            const float* __restrict__ Wq, const float* __restrict__ Wk,
                            const float* __restrict__ bk, const float* __restrict__ Wv,
                            const float* __restrict__ bv, const float* __restrict__ Wo,
                            float* __restrict__ ws) {
    const int gid = blockIdx.x * 256 + threadIdx.x;
    float* WqT = ws;
    float* WoT = ws + 4096;
    float* khs = ws + 8192;
    float* vh  = ws + 8704;
    double* zg = (double*)(ws + 9216);
    for (int idx = gid; idx < 4096; idx += 8 * 256) {
        int a = idx >> 6, b = idx & 63;
        WqT[idx] = Wq[b * 64 + a];
        WoT[idx] = Wo[b * 64 + a];
    }
    for (int idx = gid; idx < 512; idx += 8 * 256) {
        int b = idx >> 6, c = idx & 63;
        float dk = 0.f, dv = 0.f;
        #pragma unroll 8
        for (int j = 0; j < 64; ++j) {
            dk = fmaf(kin[b * 64 + j], Wk[c * 64 + j], dk);
            dv = fmaf(vin[b * 64 + j], Wv[c * 64 + j], dv);
        }
        khs[idx] = (dk + bk[c]) * SCALE;
        vh[idx]  = dv + bv[c];
        zg[idx]  = 0.0;
    }
}

// passA: e = exp((q@Wq.T + bq) * khs[batch]) -> e_out (aliases d_out), z-accum (f64 global)
// Per wave: lane = (tx channel-quad, ky k-slice). W in 64 VGPRs; q tile staged linearly;
// cross-k reduction through a private per-wave LDS scratch (no barrier needed).
__global__ __launch_bounds__(256, 4) void passA_kernel(const float* __restrict__ q,
                                                       const int* __restrict__ batch,
                                                       const float* __restrict__ bq,
                                                       float* __restrict__ ws,
                                                       float* __restrict__ e_out) {
    __shared__ __align__(16) float qtile[4096];      // [64 pts][64 k], linear
    __shared__ __align__(16) float4 red[4 * 272];    // per-wave reduce scratch (17-stride pad)
    __shared__ __align__(16) float zred[256];

    const float* WqT   = ws;
    const float* khs_g = ws + 8192;
    double* zg = (double*)(ws + 9216);

    const int tid  = threadIdx.x;
    const int wid  = tid >> 6;
    const int lane = tid & 63;
    const int tx   = lane & 15;   // channels 4tx..4tx+3
    const int ky   = lane >> 4;   // k rows 16ky..16ky+15

    float4* redw = red + wid * 272;

    // W fragment in registers: wr[kk] = WqT[16ky+kk][4tx..4tx+3]
    float4 wr[16];
    #pragma unroll
    for (int kk = 0; kk < 16; ++kk)
        wr[kk] = *(const float4*)&WqT[(ky * 16 + kk) * 64 + 4 * tx];

    const float4 bq4 = ((const float4*)bq)[tx];

    float4 zacc = make_float4(0.f, 0.f, 0.f, 0.f);
    int cur_b = -1;

    // block-uniform call sites only
    auto flushz = [&](int b) {
        if (b < 0) return;
        float4 v = zacc;
        v.x += __shfl_xor(v.x, 16); v.y += __shfl_xor(v.y, 16);
        v.z += __shfl_xor(v.z, 16); v.w += __shfl_xor(v.w, 16);
        v.x += __shfl_xor(v.x, 32); v.y += __shfl_xor(v.y, 32);
        v.z += __shfl_xor(v.z, 32); v.w += __shfl_xor(v.w, 32);
        __syncthreads();                 // zred reuse guard
        if (ky == 0) *(float4*)&zred[wid * 64 + 4 * tx] = v;
        __syncthreads();
        if (tid < 64) {
            float s = zred[tid] + zred[64 + tid] + zred[128 + tid] + zred[192 + tid];
            unsafeAtomicAdd(&zg[b * 64 + tid], (double)s);
        }
        zacc = make_float4(0.f, 0.f, 0.f, 0.f);
    };

    const int t0 = blockIdx.x * TPB;
    const int t1 = (t0 + TPB < NTILES) ? (t0 + TPB) : NTILES;

    for (int t = t0; t < t1; ++t) {
        const int p0g = t * 64;

        // linear stage of the q tile (pure memcpy, zero-fill past NPTS)
        #pragma unroll
        for (int i = 0; i < 4; ++i) {
            const int g4 = t * 1024 + i * 256 + tid;
            float4 v = make_float4(0.f, 0.f, 0.f, 0.f);
            if (g4 < Q4TOT) v = ((const float4*)q)[g4];
            ((float4*)qtile)[i * 256 + tid] = v;
        }
        const int b_lo = batch[p0g];
        const int b_hi = batch[(p0g + 63 < NPTS) ? (p0g + 63) : (NPTS - 1)];
        const bool uni = (b_lo == b_hi);
        __syncthreads();

        if (uni) {
            if (cur_b != b_lo) { flushz(cur_b); cur_b = b_lo; }
        } else {
            flushz(cur_b);
            cur_b = -1;
        }

        const float4 kh4 = *(const float4*)&khs_g[b_lo * 64 + 4 * tx];

        for (int pass = 0; pass < 4; ++pass) {
            const int pl0 = wid * 16 + pass * 4;   // tile-local first point of pass
            float4 acc[4];
            #pragma unroll
            for (int i = 0; i < 4; ++i) acc[i] = make_float4(0.f, 0.f, 0.f, 0.f);

            #pragma unroll
            for (int i = 0; i < 4; ++i) {
                const float4* r = (const float4*)(qtile + (pl0 + i) * 64 + ky * 16);
                const float4 a0 = r[0], a1 = r[1], a2 = r[2], a3 = r[3];
                FMABLK(acc[i], a0, a1, a2, a3);
            }

            // cross-k reduce via per-wave scratch (same-wave DS is in-order; fence the compiler)
            #pragma unroll
            for (int i = 0; i < 4; ++i) redw[(i * 4 + ky) * 17 + tx] = acc[i];
            asm volatile("" ::: "memory");
            const float4 s0 = redw[(ky * 4 + 0) * 17 + tx];
            const float4 s1 = redw[(ky * 4 + 1) * 17 + tx];
            const float4 s2 = redw[(ky * 4 + 2) * 17 + tx];
            const float4 s3 = redw[(ky * 4 + 3) * 17 + tx];
            float4 s;
            s.x = (s0.x + s1.x) + (s2.x + s3.x);
            s.y = (s0.y + s1.y) + (s2.y + s3.y);
            s.z = (s0.z + s1.z) + (s2.z + s3.z);
            s.w = (s0.w + s1.w) + (s2.w + s3.w);

            const int gp = p0g + pl0 + ky;          // this lane's point
            const bool valid = (gp < NPTS);

            if (uni) {
                float4 e4;
                e4.x = valid ? __expf((s.x + bq4.x) * kh4.x) : 0.f;
                e4.y = valid ? __expf((s.y + bq4.y) * kh4.y) : 0.f;
                e4.z = valid ? __expf((s.z + bq4.z) * kh4.z) : 0.f;
                e4.w = valid ? __expf((s.w + bq4.w) * kh4.w) : 0.f;
                if (valid) ((float4*)e_out)[gp * 16 + tx] = e4;
                zacc.x += e4.x; zacc.y += e4.y; zacc.z += e4.z; zacc.w += e4.w;
            } else {
                // rare boundary tile (<=7 in the whole grid)
                const int bpt = batch[valid ? gp : (NPTS - 1)];
                const float4 kh = *(const float4*)&khs_g[bpt * 64 + 4 * tx];
                float4 e4;
                e4.x = __expf((s.x + bq4.x) * kh.x);
                e4.y = __expf((s.y + bq4.y) * kh.y);
                e4.z = __expf((s.z + bq4.z) * kh.z);
                e4.w = __expf((s.w + bq4.w) * kh.w);
                if (valid) {
                    ((float4*)e_out)[gp * 16 + tx] = e4;
                    unsafeAtomicAdd(&zg[bpt * 64 + 4 * tx + 0], (double)e4.x);
                    unsafeAtomicAdd(&zg[bpt * 64 + 4 * tx + 1], (double)e4.y);
                    unsafeAtomicAdd(&zg[bpt * 64 + 4 * tx + 2], (double)e4.z);
                    unsafeAtomicAdd(&zg[bpt * 64 + 4 * tx + 3], (double)e4.w);
                }
            }
        }
        __syncthreads();   // qtile about to be restaged
    }
    flushz(cur_b);
}

// passB: out = (e * (vh/z)[batch]) @ Wo.T + bo ; e read from d_out, out written in place.
// Same structure as passA; vh/z is folded into the W registers per segment (batch sorted ->
// ~1 refold per block), so staging stays a pure linear copy.
__global__ __launch_bounds__(256, 4) void passB_kernel(const int* __restrict__ batch,
                                                       const float* __restrict__ bo,
                                                       const float* __restrict__ ws,
                                                       float* __restrict__ out) {
    __shared__ __align__(16) float ttile[4096];
    __shared__ __align__(16) float4 red[4 * 272];
    __shared__ __align__(16) float w_l[512];

    const float* WoT  = ws + 4096;
    const float* vh_g = ws + 8704;
    const double* zg  = (const double*)(ws + 9216);

    const int tid  = threadIdx.x;
    const int wid  = tid >> 6;
    const int lane = tid & 63;
    const int tx   = lane & 15;
    const int ky   = lane >> 4;

    float4* redw = red + wid * 272;

    for (int idx = tid; idx < 512; idx += 256)
        w_l[idx] = (float)((double)vh_g[idx] / zg[idx]);

    const float4 bo4 = ((const float4*)bo)[tx];

    float4 wr[16];
    int wb = -2;   // -2 unloaded, -1 raw, else folded for segment wb

    const int t0 = blockIdx.x * TPB;
    const int t1 = (t0 + TPB < NTILES) ? (t0 + TPB) : NTILES;

    __syncthreads();   // w_l ready

    for (int t = t0; t < t1; ++t) {
        const int p0g = t * 64;

        #pragma unroll
        for (int i = 0; i < 4; ++i) {
            const int g4 = t * 1024 + i * 256 + tid;
            float4 v = make_float4(0.f, 0.f, 0.f, 0.f);
            if (g4 < Q4TOT) v = ((const float4*)out)[g4];
            ((float4*)ttile)[i * 256 + tid] = v;
        }
        const int b_lo = batch[p0g];
        const int b_hi = batch[(p0g + 63 < NPTS) ? (p0g + 63) : (NPTS - 1)];
        const bool uni = (b_lo == b_hi);
        __syncthreads();

        if (uni) {
            if (wb != b_lo) {
                #pragma unroll
                for (int kk = 0; kk < 16; ++kk) {
                    const float m = w_l[b_lo * 64 + ky * 16 + kk];
                    float4 wv = *(const float4*)&WoT[(ky * 16 + kk) * 64 + 4 * tx];
                    wv.x *= m; wv.y *= m; wv.z *= m; wv.w *= m;
                    wr[kk] = wv;
                }
                wb = b_lo;
            }
        } else if (wb != -1) {
            #pragma unroll
            for (int kk = 0; kk < 16; ++kk)
                wr[kk] = *(const float4*)&WoT[(ky * 16 + kk) * 64 + 4 * tx];
            wb = -1;
        }

        for (int pass = 0; pass < 4; ++pass) {
            const int pl0 = wid * 16 + pass * 4;
            float4 acc[4];
            #pragma unroll
            for (int i = 0; i < 4; ++i) acc[i] = make_float4(0.f, 0.f, 0.f, 0.f);

            #pragma unroll
            for (int i = 0; i < 4; ++i) {
                const float4* r = (const float4*)(ttile + (pl0 + i) * 64 + ky * 16);
                float4 a0 = r[0], a1 = r[1], a2 = r[2], a3 = r[3];
                if (!uni) {
                    // boundary tile: per-point w multiply on the A side (wr is raw)
                    const int gpi = p0g + pl0 + i;
                    const int bp = batch[(gpi < NPTS) ? gpi : (NPTS - 1)];
                    const float4* wrow = (const float4*)&w_l[bp * 64 + ky * 16];
                    const float4 m0 = wrow[0], m1 = wrow[1], m2 = wrow[2], m3 = wrow[3];
                    a0.x *= m0.x; a0.y *= m0.y; a0.z *= m0.z; a0.w *= m0.w;
                    a1.x *= m1.x; a1.y *= m1.y; a1.z *= m1.z; a1.w *= m1.w;
                    a2.x *= m2.x; a2.y *= m2.y; a2.z *= m2.z; a2.w *= m2.w;
                    a3.x *= m3.x; a3.y *= m3.y; a3.z *= m3.z; a3.w *= m3.w;
                }
                FMABLK(acc[i], a0, a1, a2, a3);
            }

            #pragma unroll
            for (int i = 0; i < 4; ++i) redw[(i * 4 + ky) * 17 + tx] = acc[i];
            asm volatile("" ::: "memory");
            const float4 s0 = redw[(ky * 4 + 0) * 17 + tx];
            const float4 s1 = redw[(ky * 4 + 1) * 17 + tx];
            const float4 s2 = redw[(ky * 4 + 2) * 17 + tx];
            const float4 s3 = redw[(ky * 4 + 3) * 17 + tx];

            const int gp = p0g + pl0 + ky;
            if (gp < NPTS) {
                float4 o;
                o.x = ((s0.x + s1.x) + (s2.x + s3.x)) + bo4.x;
                o.y = ((s0.y + s1.y) + (s2.y + s3.y)) + bo4.y;
                o.z = ((s0.z + s1.z) + (s2.z + s3.z)) + bo4.z;
                o.w = ((s0.w + s1.w) + (s2.w + s3.w)) + bo4.w;
                ((float4*)out)[gp * 16 + tx] = o;
            }
        }
        __syncthreads();   // ttile about to be restaged
    }
}

extern "C" void kernel_launch(void* const* d_in, const int* in_sizes, int n_in,
                              void* d_out, int out_size, void* d_ws, size_t ws_size,
                              hipStream_t stream) {
    const float* q   = (const float*)d_in[0];
    const float* k   = (const float*)d_in[1];
    const float* v   = (const float*)d_in[2];
    const float* Wq  = (const float*)d_in[3];
    const float* bq  = (const float*)d_in[4];
    const float* Wk  = (const float*)d_in[5];
    const float* bk  = (const float*)d_in[6];
    const float* Wv  = (const float*)d_in[7];
    const float* bv  = (const float*)d_in[8];
    const float* Wo  = (const float*)d_in[9];
    const float* bo  = (const float*)d_in[10];
    const int*  batch = (const int*)d_in[11];
    float* out = (float*)d_out;
    float* ws  = (float*)d_ws;

    prep_kernel<<<8, 256, 0, stream>>>(k, v, Wq, Wk, bk, Wv, bv, Wo, ws);
    passA_kernel<<<GRID, 256, 0, stream>>>(q, batch, bq, ws, out);
    passB_kernel<<<GRID, 256, 0, stream>>>(batch, bo, ws, out);
}